// Round 13
// baseline (390.832 us; speedup 1.0000x reference)
//
#include <hip/hip_runtime.h>

#define BB 32
#define TT 243
#define JJ 17
#define CC 256
#define BJC (BB*JJ)          // 544
#define MM (BJC*TT)          // 132192 rows (compact: r = bj*TT + t)
#define FR (BJC*256)         // 139264 padded flat rows: flat = bj*256 + t
#define SIMP 244             // padded sim row stride
#define NEG_INF (-3.0e38f)

typedef __attribute__((ext_vector_type(8))) short bf16x8;
typedef __attribute__((ext_vector_type(4))) float f32x4;
typedef __attribute__((ext_vector_type(8))) _Float16 f16x8;
typedef __attribute__((ext_vector_type(4))) _Float16 f16x4;

__device__ __forceinline__ unsigned short f2bf(float f) {
  unsigned int u = __float_as_uint(f);
  u = (u + 0x7fffu + ((u >> 16) & 1u)) >> 16;   // RNE
  return (unsigned short)u;
}
__device__ __forceinline__ float bf2f(unsigned short s) {
  return __uint_as_float(((unsigned int)s) << 16);
}

// async global->LDS, 16B per lane: lds dest = uniform base + lane*16
__device__ __forceinline__ void gld16(const void* g, void* l) {
  __builtin_amdgcn_global_load_lds(
      (__attribute__((address_space(1))) void*)(g),
      (__attribute__((address_space(3))) void*)(l), 16, 0, 0);
}

// ---------- K0a: W_u,W_v f32 [C,C] -> wcp f16 [4 ksteps][512][64] (swizzled) ----------
__launch_bounds__(256)
__global__ void k_prep_w(const float* __restrict__ Wu, const float* __restrict__ Wv,
                         _Float16* __restrict__ wcp) {
  const int r = blockIdx.x * 4 + (threadIdx.x >> 6);   // 0..511
  const int l = threadIdx.x & 63;
  const float* src = ((r < CC) ? (Wu + (size_t)r * CC) : (Wv + (size_t)(r - CC) * CC)) + l * 4;
  float4 v = *reinterpret_cast<const float4*>(src);
  f16x4 hv = (f16x4){(_Float16)v.x, (_Float16)v.y, (_Float16)v.z, (_Float16)v.w};
  const int ks = l >> 4;                 // k-plane 0..3 (64 f16 each)
  const int u  = (l & 15) >> 1;          // 16B unit 0..7
  const int s  = u ^ (r & 7);            // bank swizzle slot
  *reinterpret_cast<f16x4*>(wcp + ((size_t)ks * 512 + r) * 64 + s * 8 + (l & 1) * 4) = hv;
}

// ---------- K0b: x -> xqh/xql (f16 hi + residual lo), panel-padded flat layout ----------
// layout: [ks=4][flat=bj*256+t][8 units*8 f16]; unit u at slot u^(t&7).
__launch_bounds__(256)
__global__ void k_prep_x(const float* __restrict__ x,
                         _Float16* __restrict__ xqh, _Float16* __restrict__ xql) {
  const int r = blockIdx.x * 4 + (threadIdx.x >> 6);   // compact row 0..MM-1
  const int l = threadIdx.x & 63;
  const int bj = r / TT, t = r - bj * TT;
  const int b = bj / JJ, j = bj - b * JJ;
  float4 v = *reinterpret_cast<const float4*>(
      x + ((size_t)(b * TT + t) * JJ + j) * CC + l * 4);
  _Float16 h0 = (_Float16)v.x, h1 = (_Float16)v.y, h2 = (_Float16)v.z, h3 = (_Float16)v.w;
  f16x4 hv = (f16x4){h0, h1, h2, h3};
  f16x4 lv = (f16x4){(_Float16)(v.x - (float)h0), (_Float16)(v.y - (float)h1),
                     (_Float16)(v.z - (float)h2), (_Float16)(v.w - (float)h3)};
  const int fr = bj * 256 + t;            // padded flat row
  const int ks = l >> 4;
  const int u  = (l & 15) >> 1;
  const int s  = u ^ (t & 7);             // == fr&7 since bj*256 % 8 == 0
  const size_t off = ((size_t)ks * FR + fr) * 64 + s * 8 + (l & 1) * 4;
  *reinterpret_cast<f16x4*>(xqh + off) = hv;
  *reinterpret_cast<f16x4*>(xql + off) = lv;
}

// ---------- K2: sim = xr @ xr^T per bj, row-half blocks for 2 blocks/CU ----------
// grid (2, BJC): block = 128 rows x 256 cols of one bj panel; stages the FULL
// 256-row panel (A rows are a subset of B rows). Wave tile 64x64 -> acc[4][4]
// = 64 AGPR, total regs <=128 -> 4 waves/SIMD (2 blocks/CU): stage/store of
// one block overlaps MFMA of the other. k-order identical -> sim bitwise same.
__launch_bounds__(512, 4)
__global__ void k_sim(const _Float16* __restrict__ xqh, const _Float16* __restrict__ xql,
                      float* __restrict__ sim) {
  __shared__ _Float16 Sh[256 * 64];   // 32 KB
  __shared__ _Float16 Sl[256 * 64];   // 32 KB
  const int rh = blockIdx.x;          // row half 0/1
  const int bj = blockIdx.y;
  const int tid = threadIdx.x, lane = tid & 63, wid = tid >> 6;
  const int wr = wid >> 2, wc = wid & 3;          // wave tile: 64 rows x 64 cols
  const int rowbase = rh * 128 + wr * 64;
  const int l15 = lane & 15, lg = lane >> 4;
  const size_t rb = (size_t)bj * 256;             // 8-aligned panel base
  const size_t lsrc = (size_t)(lane >> 3) * 64 + (lane & 7) * 8;

  f32x4 acc[4][4];
  #pragma unroll
  for (int i = 0; i < 4; i++)
    #pragma unroll
    for (int j = 0; j < 4; j++) acc[i][j] = (f32x4){0.f, 0.f, 0.f, 0.f};

  for (int ks = 0; ks < 4; ++ks) {
    {  // stage full 256-row panel k-slice (32 chunks x 1KB per plane, 4/wave)
      const _Float16* ph = xqh + ((size_t)ks * FR + rb) * 64;
      const _Float16* pl = xql + ((size_t)ks * FR + rb) * 64;
      #pragma unroll
      for (int c = 0; c < 4; ++c) {
        const int row0 = (wid * 4 + c) * 8;
        gld16(ph + (size_t)row0 * 64 + lsrc, &Sh[row0 * 64]);
        gld16(pl + (size_t)row0 * 64 + lsrc, &Sl[row0 * 64]);
      }
    }
    __syncthreads();                              // drains vmcnt -> tile ready
    #pragma unroll
    for (int kh = 0; kh < 2; ++kh) {
      f16x8 bhv[4], blv[4];
      #pragma unroll
      for (int j = 0; j < 4; ++j) {
        int rc = wc * 64 + j * 16 + l15;
        int sl = ((kh * 4 + lg) ^ (rc & 7)) * 8;
        bhv[j] = *reinterpret_cast<const f16x8*>(&Sh[rc * 64 + sl]);
        blv[j] = *reinterpret_cast<const f16x8*>(&Sl[rc * 64 + sl]);
      }
      #pragma unroll
      for (int i = 0; i < 4; ++i) {
        int rl = rowbase + i * 16 + l15;
        int sl = ((kh * 4 + lg) ^ (rl & 7)) * 8;
        f16x8 ah = *reinterpret_cast<const f16x8*>(&Sh[rl * 64 + sl]);
        f16x8 al = *reinterpret_cast<const f16x8*>(&Sl[rl * 64 + sl]);
        #pragma unroll
        for (int j = 0; j < 4; ++j) {
          acc[i][j] = __builtin_amdgcn_mfma_f32_16x16x32_f16(ah, bhv[j], acc[i][j], 0, 0, 0);
          acc[i][j] = __builtin_amdgcn_mfma_f32_16x16x32_f16(ah, blv[j], acc[i][j], 0, 0, 0);
          acc[i][j] = __builtin_amdgcn_mfma_f32_16x16x32_f16(al, bhv[j], acc[i][j], 0, 0, 0);
        }
      }
    }
    if (ks < 3) __syncthreads();                  // readers done before restage
  }

  const size_t sbase = (size_t)bj * TT * SIMP;
  #pragma unroll
  for (int i = 0; i < 4; ++i) {
    #pragma unroll
    for (int q = 0; q < 4; ++q) {
      int n = rowbase + i * 16 + lg * 4 + q;
      if (n < TT) {
        #pragma unroll
        for (int j = 0; j < 4; ++j) {
          int c = wc * 64 + j * 16 + l15;
          if (c < TT) sim[sbase + (size_t)n * SIMP + c] = acc[i][j][q];
        }
      }
    }
  }
}

// ---------- K1: u,v = x @ [Wu;Wv]^T + b  (f16 MFMA, staged, BK=64) ----------
__launch_bounds__(256)
__global__ void k_uv(const _Float16* __restrict__ xqh, const _Float16* __restrict__ wcp,
                     const float* __restrict__ bu, const float* __restrict__ bv,
                     unsigned short* __restrict__ uo, unsigned short* __restrict__ vo) {
  __shared__ _Float16 S[2][128][64];             // A rows, B(weight) rows
  const int ct = blockIdx.x;                     // 0..3
  const int m0 = blockIdx.y * 128;               // padded flat row base
  const int tid = threadIdx.x, lane = tid & 63, wid = tid >> 6;
  const int rm = wid * 32;
  const int l15 = lane & 15, lg = lane >> 4;

  const float* bsrc = (ct < 2) ? bu : bv;
  unsigned short* osrc = (ct < 2) ? uo : vo;
  const int cb = (ct & 1) * 128;

  float bias[8];
  #pragma unroll
  for (int j = 0; j < 8; ++j) bias[j] = bsrc[cb + j * 16 + l15];

  f32x4 acc[2][8];
  #pragma unroll
  for (int i = 0; i < 2; i++)
    #pragma unroll
    for (int j = 0; j < 8; j++) acc[i][j] = (f32x4){0.f, 0.f, 0.f, 0.f};

  for (int ks = 0; ks < 4; ++ks) {
    #pragma unroll
    for (int c = 0; c < 8; ++c) {
      int ch = wid * 8 + c;
      int half = ch >> 4;
      int rows0 = (ch & 15) * 8;
      const _Float16* g = half
        ? wcp + ((size_t)ks * 512 + ct * 128 + rows0) * 64 + lane * 8
        : xqh + ((size_t)ks * FR  + m0       + rows0) * 64 + lane * 8;
      gld16(g, &S[half][rows0][0]);
    }
    __syncthreads();
    #pragma unroll
    for (int kh = 0; kh < 2; ++kh) {
      f16x8 af[2], bfv[8];
      #pragma unroll
      for (int i = 0; i < 2; ++i) {
        int rl = rm + i * 16 + l15;
        af[i] = *reinterpret_cast<const f16x8*>(&S[0][rl][((kh * 4 + lg) ^ (rl & 7)) * 8]);
      }
      #pragma unroll
      for (int j = 0; j < 8; ++j) {
        int rl = j * 16 + l15;
        bfv[j] = *reinterpret_cast<const f16x8*>(&S[1][rl][((kh * 4 + lg) ^ (rl & 7)) * 8]);
      }
      #pragma unroll
      for (int i = 0; i < 2; ++i)
        #pragma unroll
        for (int j = 0; j < 8; ++j)
          acc[i][j] = __builtin_amdgcn_mfma_f32_16x16x32_f16(af[i], bfv[j], acc[i][j], 0, 0, 0);
    }
    __syncthreads();
  }

  #pragma unroll
  for (int i = 0; i < 2; ++i) {
    #pragma unroll
    for (int q = 0; q < 4; ++q) {
      int gf = m0 + rm + i * 16 + lg * 4 + q;    // padded flat row
      int t = gf & 255, bj = gf >> 8;
      if (t < TT) {
        size_t gm = (size_t)bj * TT + t;         // compact row
        #pragma unroll
        for (int j = 0; j < 8; ++j)
          osrc[gm * CC + cb + j * 16 + l15] = f2bf(acc[i][j][q] + bias[j]);
      }
    }
  }
}

// ---------- K3a: thr via bitonic top-4 butterfly; dis, deg, nbr list, masks ----------
__launch_bounds__(256)
__global__ void k_topk(const float* __restrict__ sim,
                       float* __restrict__ dis_o,
                       unsigned long long* __restrict__ mask_o,
                       unsigned char* __restrict__ nbr_o,
                       unsigned char* __restrict__ deg_o) {
  const int l = threadIdx.x & 63, wv = threadIdx.x >> 6;
  const int r = blockIdx.x * 4 + wv;               // MM % 4 == 0
  const float* row = sim + (size_t)r * SIMP;
  float o0 = row[l];
  float o1 = row[l + 64];
  float o2 = row[l + 128];
  float o3 = (l + 192 < TT) ? row[l + 192] : NEG_INF;
  // sort in-lane desc (5-comparator network)
  float v0 = o0, v1 = o1, v2 = o2, v3 = o3;
  { float mx, mn;
    mx=fmaxf(v0,v1); mn=fminf(v0,v1); v0=mx; v1=mn;
    mx=fmaxf(v2,v3); mn=fminf(v2,v3); v2=mx; v3=mn;
    mx=fmaxf(v0,v2); mn=fminf(v0,v2); v0=mx; v2=mn;
    mx=fmaxf(v1,v3); mn=fminf(v1,v3); v1=mx; v3=mn;
    mx=fmaxf(v1,v2); mn=fminf(v1,v2); v1=mx; v2=mn; }
  // butterfly merge: keep sorted top-4 multiset; t_i = max(a_i, b_{3-i}) is
  // bitonic -> 4-comparator bitonic sort. 6 steps -> all lanes hold top-4.
  #pragma unroll
  for (int off = 1; off < 64; off <<= 1) {
    float b0 = __shfl_xor(v0, off), b1 = __shfl_xor(v1, off),
          b2 = __shfl_xor(v2, off), b3 = __shfl_xor(v3, off);
    float t0 = fmaxf(v0, b3), t1 = fmaxf(v1, b2),
          t2 = fmaxf(v2, b1), t3 = fmaxf(v3, b0);
    float mx, mn;
    mx=fmaxf(t0,t2); mn=fminf(t0,t2); t0=mx; t2=mn;
    mx=fmaxf(t1,t3); mn=fminf(t1,t3); t1=mx; t3=mn;
    mx=fmaxf(t0,t1); mn=fminf(t0,t1); t0=mx; t1=mn;
    mx=fmaxf(t2,t3); mn=fminf(t2,t3); t2=mx; t3=mn;
    v0=t0; v1=t1; v2=t2; v3=t3;
  }
  const float thr = v3;                            // 4th largest (w/ duplicates)

  unsigned long long m0 = __ballot(o0 >= thr);
  unsigned long long m1 = __ballot(o1 >= thr);
  unsigned long long m2 = __ballot(o2 >= thr);
  unsigned long long m3 = __ballot(o3 >= thr);
  const unsigned long long below = (1ull << l) - 1ull;
  const int b0 = __popcll(m0);
  const int b1 = b0 + __popcll(m1);
  const int b2 = b1 + __popcll(m2);
  const size_t r8 = (size_t)r * 8;
  if (o0 >= thr) { int q = __popcll(m0 & below);      if (q < 8) nbr_o[r8 + q] = (unsigned char)l; }
  if (o1 >= thr) { int q = b0 + __popcll(m1 & below); if (q < 8) nbr_o[r8 + q] = (unsigned char)(64 + l); }
  if (o2 >= thr) { int q = b1 + __popcll(m2 & below); if (q < 8) nbr_o[r8 + q] = (unsigned char)(128 + l); }
  if (o3 >= thr) { int q = b2 + __popcll(m3 & below); if (q < 8) nbr_o[r8 + q] = (unsigned char)(192 + l); }
  if (l == 0) {
    int deg = b2 + __popcll(m3);
    dis_o[r] = rsqrtf((float)deg);
    deg_o[r] = (unsigned char)((deg > 255) ? 255 : deg);
    mask_o[(size_t)r * 4 + 0] = m0;
    mask_o[(size_t)r * 4 + 1] = m1;
    mask_o[(size_t)r * 4 + 2] = m2;
    mask_o[(size_t)r * 4 + 3] = m3;
  }
}

// ---------- K3b: h = norm_adj @ v + u  (list gather: independent loads) ----------
__launch_bounds__(512)
__global__ void k_agg(const unsigned char* __restrict__ nbr,
                      const unsigned char* __restrict__ degv,
                      const unsigned long long* __restrict__ mask,
                      const float* __restrict__ dis,
                      const unsigned short* __restrict__ u,
                      const unsigned short* __restrict__ v,
                      unsigned short* __restrict__ h,
                      float* __restrict__ p1, float* __restrict__ p2) {
  __shared__ float dis_l[256];
  const int bj = blockIdx.x;
  const int tid = threadIdx.x, lane = tid & 63, wid = tid >> 6;
  if (tid < TT) dis_l[tid] = dis[(size_t)bj * TT + tid];
  __syncthreads();
  const int start = blockIdx.y * 122;
  const int cnt = blockIdx.y ? (TT - 122) : 122;
  const size_t pbase = (size_t)bj * TT;
  const int co = lane * 4;
  for (int rl = wid; rl < cnt; rl += 8) {
    const int t = start + rl;
    const size_t r = pbase + t;
    const float dr = dis_l[t];
    const int dg = degv[r];
    const unsigned long long nb = *reinterpret_cast<const unsigned long long*>(nbr + r * 8);
    ushort4 uu = *reinterpret_cast<const ushort4*>(u + r * CC + co);
    float a0 = bf2f(uu.x), a1 = bf2f(uu.y), a2 = bf2f(uu.z), a3 = bf2f(uu.w);
    if (dg <= 8) {
      const int i0 = (int)(nb & 255), i1 = (int)((nb >> 8) & 255),
                i2 = (int)((nb >> 16) & 255), i3 = (int)((nb >> 24) & 255);
      ushort4 w0v = *reinterpret_cast<const ushort4*>(v + (pbase + i0) * CC + co);
      ushort4 w1v = *reinterpret_cast<const ushort4*>(v + (pbase + i1) * CC + co);
      ushort4 w2v = *reinterpret_cast<const ushort4*>(v + (pbase + i2) * CC + co);
      ushort4 w3v = *reinterpret_cast<const ushort4*>(v + (pbase + i3) * CC + co);
      const float w0 = dr * dis_l[i0], w1 = dr * dis_l[i1],
                  w2 = dr * dis_l[i2], w3 = dr * dis_l[i3];
      a0 = __builtin_fmaf(w0, bf2f(w0v.x), a0); a1 = __builtin_fmaf(w0, bf2f(w0v.y), a1);
      a2 = __builtin_fmaf(w0, bf2f(w0v.z), a2); a3 = __builtin_fmaf(w0, bf2f(w0v.w), a3);
      a0 = __builtin_fmaf(w1, bf2f(w1v.x), a0); a1 = __builtin_fmaf(w1, bf2f(w1v.y), a1);
      a2 = __builtin_fmaf(w1, bf2f(w1v.z), a2); a3 = __builtin_fmaf(w1, bf2f(w1v.w), a3);
      a0 = __builtin_fmaf(w2, bf2f(w2v.x), a0); a1 = __builtin_fmaf(w2, bf2f(w2v.y), a1);
      a2 = __builtin_fmaf(w2, bf2f(w2v.z), a2); a3 = __builtin_fmaf(w2, bf2f(w2v.w), a3);
      a0 = __builtin_fmaf(w3, bf2f(w3v.x), a0); a1 = __builtin_fmaf(w3, bf2f(w3v.y), a1);
      a2 = __builtin_fmaf(w3, bf2f(w3v.z), a2); a3 = __builtin_fmaf(w3, bf2f(w3v.w), a3);
      #pragma unroll
      for (int e = 4; e < 8; ++e) {
        if (e < dg) {
          const int ix = (int)((nb >> (8 * e)) & 255);
          const float we = dr * dis_l[ix];
          ushort4 vv = *reinterpret_cast<const ushort4*>(v + (pbase + ix) * CC + co);
          a0 = __builtin_fmaf(we, bf2f(vv.x), a0); a1 = __builtin_fmaf(we, bf2f(vv.y), a1);
          a2 = __builtin_fmaf(we, bf2f(vv.z), a2); a3 = __builtin_fmaf(we, bf2f(vv.w), a3);
        }
      }
    } else {                                     // rare tie overflow: mask decode
      #pragma unroll
      for (int w4 = 0; w4 < 4; ++w4) {
        unsigned long long m = mask[r * 4 + w4];
        while (m) {
          int i = __ffsll(m) - 1;
          m &= m - 1;
          int idx = w4 * 64 + i;
          float w = dr * dis_l[idx];
          ushort4 vv = *reinterpret_cast<const ushort4*>(v + (pbase + idx) * CC + co);
          a0 = __builtin_fmaf(w, bf2f(vv.x), a0);
          a1 = __builtin_fmaf(w, bf2f(vv.y), a1);
          a2 = __builtin_fmaf(w, bf2f(vv.z), a2);
          a3 = __builtin_fmaf(w, bf2f(vv.w), a3);
        }
      }
    }
    ushort4 hh;
    hh.x = f2bf(a0); hh.y = f2bf(a1); hh.z = f2bf(a2); hh.w = f2bf(a3);
    *reinterpret_cast<ushort4*>(h + r * CC + co) = hh;
    float s1 = a0 + a1 + a2 + a3;
    float s2 = a0*a0 + a1*a1 + a2*a2 + a3*a3;
    #pragma unroll
    for (int off = 1; off < 64; off <<= 1) { s1 += __shfl_xor(s1, off); s2 += __shfl_xor(s2, off); }
    if (lane == 0) { p1[r] = s1; p2[r] = s2; }
  }
}

// ---------- K4: BN stats per t -> scale/shift ----------
__global__ void k_bnstat(const float* __restrict__ p1, const float* __restrict__ p2,
                         const float* __restrict__ gamma, const float* __restrict__ beta,
                         float* __restrict__ scale, float* __restrict__ shift) {
  __shared__ float sA[256], sB[256];
  const int t = blockIdx.x;
  const int tid = threadIdx.x;
  float a = 0.f, b2 = 0.f;
  for (int bj = tid; bj < BJC; bj += 256) {
    a  += p1[bj * TT + t];
    b2 += p2[bj * TT + t];
  }
  sA[tid] = a; sB[tid] = b2;
  __syncthreads();
  for (int s = 128; s > 0; s >>= 1) {
    if (tid < s) { sA[tid] += sA[tid + s]; sB[tid] += sB[tid + s]; }
    __syncthreads();
  }
  if (tid == 0) {
    const float invN = 1.0f / (float)(BJC * CC);
    float mean = sA[0] * invN;
    float var  = sB[0] * invN - mean * mean;
    float sc   = rsqrtf(var + 1e-5f) * gamma[t];
    scale[t] = sc;
    shift[t] = beta[t] - mean * sc;
  }
}

// ---------- K5: out = relu(x + h*scale + shift), back to [B,T,J,C] ----------
__global__ void k_out(const float* __restrict__ x, const unsigned short* __restrict__ h,
                      const float* __restrict__ scale, const float* __restrict__ shift,
                      float* __restrict__ out) {
  int g = blockIdx.x * 256 + threadIdx.x;
  if (g >= MM * (CC/4)) return;
  int c4  = g & 63;
  int rowx = g >> 6;
  int b   = rowx / (TT*JJ);
  int rem = rowx - b*(TT*JJ);
  int t   = rem / JJ;
  int j   = rem - t*JJ;
  size_t hoff = ((size_t)(b*JJ + j) * TT + t) * CC + c4*4;
  float4 xv = *reinterpret_cast<const float4*>(x + (size_t)rowx*CC + c4*4);
  ushort4 hv = *reinterpret_cast<const ushort4*>(h + hoff);
  float sc = scale[t], sh = shift[t];
  float4 o;
  o.x = fmaxf(xv.x + bf2f(hv.x)*sc + sh, 0.f);
  o.y = fmaxf(xv.y + bf2f(hv.y)*sc + sh, 0.f);
  o.z = fmaxf(xv.z + bf2f(hv.z)*sc + sh, 0.f);
  o.w = fmaxf(xv.w + bf2f(hv.w)*sc + sh, 0.f);
  *reinterpret_cast<float4*>(out + (size_t)rowx*CC + c4*4) = o;
}

extern "C" void kernel_launch(void* const* d_in, const int* in_sizes, int n_in,
                              void* d_out, int out_size, void* d_ws, size_t ws_size,
                              hipStream_t stream) {
  const float* x     = (const float*)d_in[0];
  const float* Wu    = (const float*)d_in[1];
  const float* bu    = (const float*)d_in[2];
  const float* Wv    = (const float*)d_in[3];
  const float* bv    = (const float*)d_in[4];
  const float* gamma = (const float*)d_in[5];
  const float* beta  = (const float*)d_in[6];
  float* out = (float*)d_out;

  char* ws = (char*)d_ws;
  size_t off = 0;
  auto alloc = [&](size_t bytes) -> void* {
    void* p = ws + off;
    off = (off + bytes + 255) & ~(size_t)255;
    return p;
  };
  _Float16* xqh = (_Float16*)alloc((size_t)4 * FR * 64 * 2);      // 71.3MB
  _Float16* xql = (_Float16*)alloc((size_t)4 * FR * 64 * 2);      // 71.3MB
  _Float16* wcp = (_Float16*)alloc((size_t)4 * 512 * 64 * 2);
  float* sim = (float*)alloc((size_t)BJC * TT * SIMP * 4);        // 129MB
  float* dis = (float*)alloc((size_t)MM * 4);
  unsigned long long* msk = (unsigned long long*)alloc((size_t)MM * 4 * 8);
  unsigned char* nbr = (unsigned char*)alloc((size_t)MM * 8);
  unsigned char* deg = (unsigned char*)alloc((size_t)MM);
  float* p1    = (float*)alloc((size_t)MM * 4);
  float* p2    = (float*)alloc((size_t)MM * 4);
  float* scale = (float*)alloc(1024);
  float* shift = (float*)alloc(1024);
  unsigned short* v = (unsigned short*)alloc((size_t)MM * CC * 2); // 67.7MB
  // aliases (strictly stream-ordered, rewritten every call):
  // u lives in sim's space (sim dead after k_topk; k_uv writes after topk)
  unsigned short* u = (unsigned short*)sim;
  // h lives in xql's space (xql dead after k_sim)
  unsigned short* h = (unsigned short*)xql;

  if (ws_size < off) {
    hipMemsetAsync(d_out, 0, (size_t)out_size * 4, stream);
    return;
  }

  k_prep_w<<<dim3(512/4), dim3(256), 0, stream>>>(Wu, Wv, wcp);
  k_prep_x<<<dim3(MM/4), dim3(256), 0, stream>>>(x, xqh, xql);
  k_sim  <<<dim3(2, BJC), dim3(512), 0, stream>>>(xqh, xql, sim);
  k_topk <<<dim3(MM/4), dim3(256), 0, stream>>>(sim, dis, msk, nbr, deg);
  k_uv   <<<dim3(4, FR/128), dim3(256), 0, stream>>>(xqh, wcp, bu, bv, u, v);
  k_agg  <<<dim3(BJC, 2), dim3(512), 0, stream>>>(nbr, deg, msk, dis, u, v, h, p1, p2);
  k_bnstat<<<dim3(TT), dim3(256), 0, stream>>>(p1, p2, gamma, beta, scale, shift);
  k_out  <<<dim3((MM*(CC/4) + 255)/256), dim3(256), 0, stream>>>(x, h, scale, shift, out);
}

// Round 14
// 385.482 us; speedup vs baseline: 1.0139x; 1.0139x over previous
//
#include <hip/hip_runtime.h>

#define BB 32
#define TT 243
#define JJ 17
#define CC 256
#define BJC (BB*JJ)          // 544
#define MM (BJC*TT)          // 132192 rows (compact: r = bj*TT + t)
#define FR (BJC*256)         // 139264 padded flat rows: flat = bj*256 + t
#define SIMP 244             // padded sim row stride
#define NEG_INF (-3.0e38f)

typedef __attribute__((ext_vector_type(8))) short bf16x8;
typedef __attribute__((ext_vector_type(4))) float f32x4;
typedef __attribute__((ext_vector_type(8))) _Float16 f16x8;
typedef __attribute__((ext_vector_type(4))) _Float16 f16x4;

__device__ __forceinline__ unsigned short f2bf(float f) {
  unsigned int u = __float_as_uint(f);
  u = (u + 0x7fffu + ((u >> 16) & 1u)) >> 16;   // RNE
  return (unsigned short)u;
}
__device__ __forceinline__ float bf2f(unsigned short s) {
  return __uint_as_float(((unsigned int)s) << 16);
}

// async global->LDS, 16B per lane: lds dest = uniform base + lane*16
__device__ __forceinline__ void gld16(const void* g, void* l) {
  __builtin_amdgcn_global_load_lds(
      (__attribute__((address_space(1))) void*)(g),
      (__attribute__((address_space(3))) void*)(l), 16, 0, 0);
}

// ---------- K0a: W_u,W_v f32 [C,C] -> wcp f16 [4 ksteps][512][64] (swizzled) ----------
__launch_bounds__(256)
__global__ void k_prep_w(const float* __restrict__ Wu, const float* __restrict__ Wv,
                         _Float16* __restrict__ wcp) {
  const int r = blockIdx.x * 4 + (threadIdx.x >> 6);   // 0..511
  const int l = threadIdx.x & 63;
  const float* src = ((r < CC) ? (Wu + (size_t)r * CC) : (Wv + (size_t)(r - CC) * CC)) + l * 4;
  float4 v = *reinterpret_cast<const float4*>(src);
  f16x4 hv = (f16x4){(_Float16)v.x, (_Float16)v.y, (_Float16)v.z, (_Float16)v.w};
  const int ks = l >> 4;                 // k-plane 0..3 (64 f16 each)
  const int u  = (l & 15) >> 1;          // 16B unit 0..7
  const int s  = u ^ (r & 7);            // bank swizzle slot
  *reinterpret_cast<f16x4*>(wcp + ((size_t)ks * 512 + r) * 64 + s * 8 + (l & 1) * 4) = hv;
}

// ---------- K0b: x -> xqh/xql (f16 hi + residual lo), panel-padded flat layout ----------
// layout: [ks=4][flat=bj*256+t][8 units*8 f16]; unit u at slot u^(t&7).
__launch_bounds__(256)
__global__ void k_prep_x(const float* __restrict__ x,
                         _Float16* __restrict__ xqh, _Float16* __restrict__ xql) {
  const int r = blockIdx.x * 4 + (threadIdx.x >> 6);   // compact row 0..MM-1
  const int l = threadIdx.x & 63;
  const int bj = r / TT, t = r - bj * TT;
  const int b = bj / JJ, j = bj - b * JJ;
  float4 v = *reinterpret_cast<const float4*>(
      x + ((size_t)(b * TT + t) * JJ + j) * CC + l * 4);
  _Float16 h0 = (_Float16)v.x, h1 = (_Float16)v.y, h2 = (_Float16)v.z, h3 = (_Float16)v.w;
  f16x4 hv = (f16x4){h0, h1, h2, h3};
  f16x4 lv = (f16x4){(_Float16)(v.x - (float)h0), (_Float16)(v.y - (float)h1),
                     (_Float16)(v.z - (float)h2), (_Float16)(v.w - (float)h3)};
  const int fr = bj * 256 + t;            // padded flat row
  const int ks = l >> 4;
  const int u  = (l & 15) >> 1;
  const int s  = u ^ (t & 7);             // == fr&7 since bj*256 % 8 == 0
  const size_t off = ((size_t)ks * FR + fr) * 64 + s * 8 + (l & 1) * 4;
  *reinterpret_cast<f16x4*>(xqh + off) = hv;
  *reinterpret_cast<f16x4*>(xql + off) = lv;
}

// ---------- K2: sim = xr @ xr^T per bj, row-half blocks, XCD-paired ----------
// grid 1088 1-D; mapping g=bid>>4, s=bid&15 -> bj=g*8+(s&7), rh=s>>3 puts the
// two row-half blocks of one bj on the SAME XCD (bid%8 equal) ~8 ids apart,
// so the twin's panel re-read hits that XCD's L2 instead of HBM.
// Wave tile 64x64 -> acc 64 AGPR, <=128 total regs -> 2 blocks/CU.
// k-order identical -> sim bitwise same.
__launch_bounds__(512, 4)
__global__ void k_sim(const _Float16* __restrict__ xqh, const _Float16* __restrict__ xql,
                      float* __restrict__ sim) {
  __shared__ _Float16 Sh[256 * 64];   // 32 KB
  __shared__ _Float16 Sl[256 * 64];   // 32 KB
  const int bid = blockIdx.x;
  const int g = bid >> 4, s_ = bid & 15;
  const int bj = g * 8 + (s_ & 7);    // 544 = 68*8 -> bijective
  const int rh = s_ >> 3;             // row half 0/1
  const int tid = threadIdx.x, lane = tid & 63, wid = tid >> 6;
  const int wr = wid >> 2, wc = wid & 3;          // wave tile: 64 rows x 64 cols
  const int rowbase = rh * 128 + wr * 64;
  const int l15 = lane & 15, lg = lane >> 4;
  const size_t rb = (size_t)bj * 256;             // 8-aligned panel base
  const size_t lsrc = (size_t)(lane >> 3) * 64 + (lane & 7) * 8;

  f32x4 acc[4][4];
  #pragma unroll
  for (int i = 0; i < 4; i++)
    #pragma unroll
    for (int j = 0; j < 4; j++) acc[i][j] = (f32x4){0.f, 0.f, 0.f, 0.f};

  for (int ks = 0; ks < 4; ++ks) {
    {  // stage full 256-row panel k-slice (32 chunks x 1KB per plane, 4/wave)
      const _Float16* ph = xqh + ((size_t)ks * FR + rb) * 64;
      const _Float16* pl = xql + ((size_t)ks * FR + rb) * 64;
      #pragma unroll
      for (int c = 0; c < 4; ++c) {
        const int row0 = (wid * 4 + c) * 8;
        gld16(ph + (size_t)row0 * 64 + lsrc, &Sh[row0 * 64]);
        gld16(pl + (size_t)row0 * 64 + lsrc, &Sl[row0 * 64]);
      }
    }
    __syncthreads();                              // drains vmcnt -> tile ready
    #pragma unroll
    for (int kh = 0; kh < 2; ++kh) {
      f16x8 bhv[4], blv[4];
      #pragma unroll
      for (int j = 0; j < 4; ++j) {
        int rc = wc * 64 + j * 16 + l15;
        int sl = ((kh * 4 + lg) ^ (rc & 7)) * 8;
        bhv[j] = *reinterpret_cast<const f16x8*>(&Sh[rc * 64 + sl]);
        blv[j] = *reinterpret_cast<const f16x8*>(&Sl[rc * 64 + sl]);
      }
      #pragma unroll
      for (int i = 0; i < 4; ++i) {
        int rl = rowbase + i * 16 + l15;
        int sl = ((kh * 4 + lg) ^ (rl & 7)) * 8;
        f16x8 ah = *reinterpret_cast<const f16x8*>(&Sh[rl * 64 + sl]);
        f16x8 al = *reinterpret_cast<const f16x8*>(&Sl[rl * 64 + sl]);
        #pragma unroll
        for (int j = 0; j < 4; ++j) {
          acc[i][j] = __builtin_amdgcn_mfma_f32_16x16x32_f16(ah, bhv[j], acc[i][j], 0, 0, 0);
          acc[i][j] = __builtin_amdgcn_mfma_f32_16x16x32_f16(ah, blv[j], acc[i][j], 0, 0, 0);
          acc[i][j] = __builtin_amdgcn_mfma_f32_16x16x32_f16(al, bhv[j], acc[i][j], 0, 0, 0);
        }
      }
    }
    if (ks < 3) __syncthreads();                  // readers done before restage
  }

  const size_t sbase = (size_t)bj * TT * SIMP;
  #pragma unroll
  for (int i = 0; i < 4; ++i) {
    #pragma unroll
    for (int q = 0; q < 4; ++q) {
      int n = rowbase + i * 16 + lg * 4 + q;
      if (n < TT) {
        #pragma unroll
        for (int j = 0; j < 4; ++j) {
          int c = wc * 64 + j * 16 + l15;
          if (c < TT) sim[sbase + (size_t)n * SIMP + c] = acc[i][j][q];
        }
      }
    }
  }
}

// ---------- K1: u,v = x @ [Wu;Wv]^T + b  (f16 MFMA, staged, BK=64) ----------
__launch_bounds__(256)
__global__ void k_uv(const _Float16* __restrict__ xqh, const _Float16* __restrict__ wcp,
                     const float* __restrict__ bu, const float* __restrict__ bv,
                     unsigned short* __restrict__ uo, unsigned short* __restrict__ vo) {
  __shared__ _Float16 S[2][128][64];             // A rows, B(weight) rows
  const int ct = blockIdx.x;                     // 0..3
  const int m0 = blockIdx.y * 128;               // padded flat row base
  const int tid = threadIdx.x, lane = tid & 63, wid = tid >> 6;
  const int rm = wid * 32;
  const int l15 = lane & 15, lg = lane >> 4;

  const float* bsrc = (ct < 2) ? bu : bv;
  unsigned short* osrc = (ct < 2) ? uo : vo;
  const int cb = (ct & 1) * 128;

  float bias[8];
  #pragma unroll
  for (int j = 0; j < 8; ++j) bias[j] = bsrc[cb + j * 16 + l15];

  f32x4 acc[2][8];
  #pragma unroll
  for (int i = 0; i < 2; i++)
    #pragma unroll
    for (int j = 0; j < 8; j++) acc[i][j] = (f32x4){0.f, 0.f, 0.f, 0.f};

  for (int ks = 0; ks < 4; ++ks) {
    #pragma unroll
    for (int c = 0; c < 8; ++c) {
      int ch = wid * 8 + c;
      int half = ch >> 4;
      int rows0 = (ch & 15) * 8;
      const _Float16* g = half
        ? wcp + ((size_t)ks * 512 + ct * 128 + rows0) * 64 + lane * 8
        : xqh + ((size_t)ks * FR  + m0       + rows0) * 64 + lane * 8;
      gld16(g, &S[half][rows0][0]);
    }
    __syncthreads();
    #pragma unroll
    for (int kh = 0; kh < 2; ++kh) {
      f16x8 af[2], bfv[8];
      #pragma unroll
      for (int i = 0; i < 2; ++i) {
        int rl = rm + i * 16 + l15;
        af[i] = *reinterpret_cast<const f16x8*>(&S[0][rl][((kh * 4 + lg) ^ (rl & 7)) * 8]);
      }
      #pragma unroll
      for (int j = 0; j < 8; ++j) {
        int rl = j * 16 + l15;
        bfv[j] = *reinterpret_cast<const f16x8*>(&S[1][rl][((kh * 4 + lg) ^ (rl & 7)) * 8]);
      }
      #pragma unroll
      for (int i = 0; i < 2; ++i)
        #pragma unroll
        for (int j = 0; j < 8; ++j)
          acc[i][j] = __builtin_amdgcn_mfma_f32_16x16x32_f16(af[i], bfv[j], acc[i][j], 0, 0, 0);
    }
    __syncthreads();
  }

  #pragma unroll
  for (int i = 0; i < 2; ++i) {
    #pragma unroll
    for (int q = 0; q < 4; ++q) {
      int gf = m0 + rm + i * 16 + lg * 4 + q;    // padded flat row
      int t = gf & 255, bj = gf >> 8;
      if (t < TT) {
        size_t gm = (size_t)bj * TT + t;         // compact row
        #pragma unroll
        for (int j = 0; j < 8; ++j)
          osrc[gm * CC + cb + j * 16 + l15] = f2bf(acc[i][j][q] + bias[j]);
      }
    }
  }
}

// ---------- K3a: thr via bitonic top-4 butterfly; dis, deg, nbr list, masks ----------
__launch_bounds__(256)
__global__ void k_topk(const float* __restrict__ sim,
                       float* __restrict__ dis_o,
                       unsigned long long* __restrict__ mask_o,
                       unsigned char* __restrict__ nbr_o,
                       unsigned char* __restrict__ deg_o) {
  const int l = threadIdx.x & 63, wv = threadIdx.x >> 6;
  const int r = blockIdx.x * 4 + wv;               // MM % 4 == 0
  const float* row = sim + (size_t)r * SIMP;
  float o0 = row[l];
  float o1 = row[l + 64];
  float o2 = row[l + 128];
  float o3 = (l + 192 < TT) ? row[l + 192] : NEG_INF;
  // sort in-lane desc (5-comparator network)
  float v0 = o0, v1 = o1, v2 = o2, v3 = o3;
  { float mx, mn;
    mx=fmaxf(v0,v1); mn=fminf(v0,v1); v0=mx; v1=mn;
    mx=fmaxf(v2,v3); mn=fminf(v2,v3); v2=mx; v3=mn;
    mx=fmaxf(v0,v2); mn=fminf(v0,v2); v0=mx; v2=mn;
    mx=fmaxf(v1,v3); mn=fminf(v1,v3); v1=mx; v3=mn;
    mx=fmaxf(v1,v2); mn=fminf(v1,v2); v1=mx; v2=mn; }
  // butterfly merge: keep sorted top-4 multiset; t_i = max(a_i, b_{3-i}) is
  // bitonic -> 4-comparator bitonic sort. 6 steps -> all lanes hold top-4.
  #pragma unroll
  for (int off = 1; off < 64; off <<= 1) {
    float b0 = __shfl_xor(v0, off), b1 = __shfl_xor(v1, off),
          b2 = __shfl_xor(v2, off), b3 = __shfl_xor(v3, off);
    float t0 = fmaxf(v0, b3), t1 = fmaxf(v1, b2),
          t2 = fmaxf(v2, b1), t3 = fmaxf(v3, b0);
    float mx, mn;
    mx=fmaxf(t0,t2); mn=fminf(t0,t2); t0=mx; t2=mn;
    mx=fmaxf(t1,t3); mn=fminf(t1,t3); t1=mx; t3=mn;
    mx=fmaxf(t0,t1); mn=fminf(t0,t1); t0=mx; t1=mn;
    mx=fmaxf(t2,t3); mn=fminf(t2,t3); t2=mx; t3=mn;
    v0=t0; v1=t1; v2=t2; v3=t3;
  }
  const float thr = v3;                            // 4th largest (w/ duplicates)

  unsigned long long m0 = __ballot(o0 >= thr);
  unsigned long long m1 = __ballot(o1 >= thr);
  unsigned long long m2 = __ballot(o2 >= thr);
  unsigned long long m3 = __ballot(o3 >= thr);
  const unsigned long long below = (1ull << l) - 1ull;
  const int b0 = __popcll(m0);
  const int b1 = b0 + __popcll(m1);
  const int b2 = b1 + __popcll(m2);
  const size_t r8 = (size_t)r * 8;
  if (o0 >= thr) { int q = __popcll(m0 & below);      if (q < 8) nbr_o[r8 + q] = (unsigned char)l; }
  if (o1 >= thr) { int q = b0 + __popcll(m1 & below); if (q < 8) nbr_o[r8 + q] = (unsigned char)(64 + l); }
  if (o2 >= thr) { int q = b1 + __popcll(m2 & below); if (q < 8) nbr_o[r8 + q] = (unsigned char)(128 + l); }
  if (o3 >= thr) { int q = b2 + __popcll(m3 & below); if (q < 8) nbr_o[r8 + q] = (unsigned char)(192 + l); }
  if (l == 0) {
    int deg = b2 + __popcll(m3);
    dis_o[r] = rsqrtf((float)deg);
    deg_o[r] = (unsigned char)((deg > 255) ? 255 : deg);
    mask_o[(size_t)r * 4 + 0] = m0;
    mask_o[(size_t)r * 4 + 1] = m1;
    mask_o[(size_t)r * 4 + 2] = m2;
    mask_o[(size_t)r * 4 + 3] = m3;
  }
}

// ---------- K3b: h = norm_adj @ v + u  (list gather: independent loads) ----------
__launch_bounds__(512)
__global__ void k_agg(const unsigned char* __restrict__ nbr,
                      const unsigned char* __restrict__ degv,
                      const unsigned long long* __restrict__ mask,
                      const float* __restrict__ dis,
                      const unsigned short* __restrict__ u,
                      const unsigned short* __restrict__ v,
                      unsigned short* __restrict__ h,
                      float* __restrict__ p1, float* __restrict__ p2) {
  __shared__ float dis_l[256];
  const int bj = blockIdx.x;
  const int tid = threadIdx.x, lane = tid & 63, wid = tid >> 6;
  if (tid < TT) dis_l[tid] = dis[(size_t)bj * TT + tid];
  __syncthreads();
  const int start = blockIdx.y * 122;
  const int cnt = blockIdx.y ? (TT - 122) : 122;
  const size_t pbase = (size_t)bj * TT;
  const int co = lane * 4;
  for (int rl = wid; rl < cnt; rl += 8) {
    const int t = start + rl;
    const size_t r = pbase + t;
    const float dr = dis_l[t];
    const int dg = degv[r];
    const unsigned long long nb = *reinterpret_cast<const unsigned long long*>(nbr + r * 8);
    ushort4 uu = *reinterpret_cast<const ushort4*>(u + r * CC + co);
    float a0 = bf2f(uu.x), a1 = bf2f(uu.y), a2 = bf2f(uu.z), a3 = bf2f(uu.w);
    if (dg <= 8) {
      const int i0 = (int)(nb & 255), i1 = (int)((nb >> 8) & 255),
                i2 = (int)((nb >> 16) & 255), i3 = (int)((nb >> 24) & 255);
      ushort4 w0v = *reinterpret_cast<const ushort4*>(v + (pbase + i0) * CC + co);
      ushort4 w1v = *reinterpret_cast<const ushort4*>(v + (pbase + i1) * CC + co);
      ushort4 w2v = *reinterpret_cast<const ushort4*>(v + (pbase + i2) * CC + co);
      ushort4 w3v = *reinterpret_cast<const ushort4*>(v + (pbase + i3) * CC + co);
      const float w0 = dr * dis_l[i0], w1 = dr * dis_l[i1],
                  w2 = dr * dis_l[i2], w3 = dr * dis_l[i3];
      a0 = __builtin_fmaf(w0, bf2f(w0v.x), a0); a1 = __builtin_fmaf(w0, bf2f(w0v.y), a1);
      a2 = __builtin_fmaf(w0, bf2f(w0v.z), a2); a3 = __builtin_fmaf(w0, bf2f(w0v.w), a3);
      a0 = __builtin_fmaf(w1, bf2f(w1v.x), a0); a1 = __builtin_fmaf(w1, bf2f(w1v.y), a1);
      a2 = __builtin_fmaf(w1, bf2f(w1v.z), a2); a3 = __builtin_fmaf(w1, bf2f(w1v.w), a3);
      a0 = __builtin_fmaf(w2, bf2f(w2v.x), a0); a1 = __builtin_fmaf(w2, bf2f(w2v.y), a1);
      a2 = __builtin_fmaf(w2, bf2f(w2v.z), a2); a3 = __builtin_fmaf(w2, bf2f(w2v.w), a3);
      a0 = __builtin_fmaf(w3, bf2f(w3v.x), a0); a1 = __builtin_fmaf(w3, bf2f(w3v.y), a1);
      a2 = __builtin_fmaf(w3, bf2f(w3v.z), a2); a3 = __builtin_fmaf(w3, bf2f(w3v.w), a3);
      #pragma unroll
      for (int e = 4; e < 8; ++e) {
        if (e < dg) {
          const int ix = (int)((nb >> (8 * e)) & 255);
          const float we = dr * dis_l[ix];
          ushort4 vv = *reinterpret_cast<const ushort4*>(v + (pbase + ix) * CC + co);
          a0 = __builtin_fmaf(we, bf2f(vv.x), a0); a1 = __builtin_fmaf(we, bf2f(vv.y), a1);
          a2 = __builtin_fmaf(we, bf2f(vv.z), a2); a3 = __builtin_fmaf(we, bf2f(vv.w), a3);
        }
      }
    } else {                                     // rare tie overflow: mask decode
      #pragma unroll
      for (int w4 = 0; w4 < 4; ++w4) {
        unsigned long long m = mask[r * 4 + w4];
        while (m) {
          int i = __ffsll(m) - 1;
          m &= m - 1;
          int idx = w4 * 64 + i;
          float w = dr * dis_l[idx];
          ushort4 vv = *reinterpret_cast<const ushort4*>(v + (pbase + idx) * CC + co);
          a0 = __builtin_fmaf(w, bf2f(vv.x), a0);
          a1 = __builtin_fmaf(w, bf2f(vv.y), a1);
          a2 = __builtin_fmaf(w, bf2f(vv.z), a2);
          a3 = __builtin_fmaf(w, bf2f(vv.w), a3);
        }
      }
    }
    ushort4 hh;
    hh.x = f2bf(a0); hh.y = f2bf(a1); hh.z = f2bf(a2); hh.w = f2bf(a3);
    *reinterpret_cast<ushort4*>(h + r * CC + co) = hh;
    float s1 = a0 + a1 + a2 + a3;
    float s2 = a0*a0 + a1*a1 + a2*a2 + a3*a3;
    #pragma unroll
    for (int off = 1; off < 64; off <<= 1) { s1 += __shfl_xor(s1, off); s2 += __shfl_xor(s2, off); }
    if (lane == 0) { p1[r] = s1; p2[r] = s2; }
  }
}

// ---------- K4: BN stats per t -> scale/shift ----------
__global__ void k_bnstat(const float* __restrict__ p1, const float* __restrict__ p2,
                         const float* __restrict__ gamma, const float* __restrict__ beta,
                         float* __restrict__ scale, float* __restrict__ shift) {
  __shared__ float sA[256], sB[256];
  const int t = blockIdx.x;
  const int tid = threadIdx.x;
  float a = 0.f, b2 = 0.f;
  for (int bj = tid; bj < BJC; bj += 256) {
    a  += p1[bj * TT + t];
    b2 += p2[bj * TT + t];
  }
  sA[tid] = a; sB[tid] = b2;
  __syncthreads();
  for (int s = 128; s > 0; s >>= 1) {
    if (tid < s) { sA[tid] += sA[tid + s]; sB[tid] += sB[tid + s]; }
    __syncthreads();
  }
  if (tid == 0) {
    const float invN = 1.0f / (float)(BJC * CC);
    float mean = sA[0] * invN;
    float var  = sB[0] * invN - mean * mean;
    float sc   = rsqrtf(var + 1e-5f) * gamma[t];
    scale[t] = sc;
    shift[t] = beta[t] - mean * sc;
  }
}

// ---------- K5: out = relu(x + h*scale + shift), back to [B,T,J,C] ----------
__global__ void k_out(const float* __restrict__ x, const unsigned short* __restrict__ h,
                      const float* __restrict__ scale, const float* __restrict__ shift,
                      float* __restrict__ out) {
  int g = blockIdx.x * 256 + threadIdx.x;
  if (g >= MM * (CC/4)) return;
  int c4  = g & 63;
  int rowx = g >> 6;
  int b   = rowx / (TT*JJ);
  int rem = rowx - b*(TT*JJ);
  int t   = rem / JJ;
  int j   = rem - t*JJ;
  size_t hoff = ((size_t)(b*JJ + j) * TT + t) * CC + c4*4;
  float4 xv = *reinterpret_cast<const float4*>(x + (size_t)rowx*CC + c4*4);
  ushort4 hv = *reinterpret_cast<const ushort4*>(h + hoff);
  float sc = scale[t], sh = shift[t];
  float4 o;
  o.x = fmaxf(xv.x + bf2f(hv.x)*sc + sh, 0.f);
  o.y = fmaxf(xv.y + bf2f(hv.y)*sc + sh, 0.f);
  o.z = fmaxf(xv.z + bf2f(hv.z)*sc + sh, 0.f);
  o.w = fmaxf(xv.w + bf2f(hv.w)*sc + sh, 0.f);
  *reinterpret_cast<float4*>(out + (size_t)rowx*CC + c4*4) = o;
}

extern "C" void kernel_launch(void* const* d_in, const int* in_sizes, int n_in,
                              void* d_out, int out_size, void* d_ws, size_t ws_size,
                              hipStream_t stream) {
  const float* x     = (const float*)d_in[0];
  const float* Wu    = (const float*)d_in[1];
  const float* bu    = (const float*)d_in[2];
  const float* Wv    = (const float*)d_in[3];
  const float* bv    = (const float*)d_in[4];
  const float* gamma = (const float*)d_in[5];
  const float* beta  = (const float*)d_in[6];
  float* out = (float*)d_out;

  char* ws = (char*)d_ws;
  size_t off = 0;
  auto alloc = [&](size_t bytes) -> void* {
    void* p = ws + off;
    off = (off + bytes + 255) & ~(size_t)255;
    return p;
  };
  _Float16* xqh = (_Float16*)alloc((size_t)4 * FR * 64 * 2);      // 71.3MB
  _Float16* xql = (_Float16*)alloc((size_t)4 * FR * 64 * 2);      // 71.3MB
  _Float16* wcp = (_Float16*)alloc((size_t)4 * 512 * 64 * 2);
  float* sim = (float*)alloc((size_t)BJC * TT * SIMP * 4);        // 129MB
  float* dis = (float*)alloc((size_t)MM * 4);
  unsigned long long* msk = (unsigned long long*)alloc((size_t)MM * 4 * 8);
  unsigned char* nbr = (unsigned char*)alloc((size_t)MM * 8);
  unsigned char* deg = (unsigned char*)alloc((size_t)MM);
  float* p1    = (float*)alloc((size_t)MM * 4);
  float* p2    = (float*)alloc((size_t)MM * 4);
  float* scale = (float*)alloc(1024);
  float* shift = (float*)alloc(1024);
  unsigned short* v = (unsigned short*)alloc((size_t)MM * CC * 2); // 67.7MB
  // aliases (strictly stream-ordered, rewritten every call):
  // u lives in sim's space (sim dead after k_topk; k_uv writes after topk)
  unsigned short* u = (unsigned short*)sim;
  // h lives in xql's space (xql dead after k_sim)
  unsigned short* h = (unsigned short*)xql;

  if (ws_size < off) {
    hipMemsetAsync(d_out, 0, (size_t)out_size * 4, stream);
    return;
  }

  k_prep_w<<<dim3(512/4), dim3(256), 0, stream>>>(Wu, Wv, wcp);
  k_prep_x<<<dim3(MM/4), dim3(256), 0, stream>>>(x, xqh, xql);
  k_sim  <<<dim3(BJC*2), dim3(512), 0, stream>>>(xqh, xql, sim);
  k_topk <<<dim3(MM/4), dim3(256), 0, stream>>>(sim, dis, msk, nbr, deg);
  k_uv   <<<dim3(4, FR/128), dim3(256), 0, stream>>>(xqh, wcp, bu, bv, u, v);
  k_agg  <<<dim3(BJC, 2), dim3(512), 0, stream>>>(nbr, deg, msk, dis, u, v, h, p1, p2);
  k_bnstat<<<dim3(TT), dim3(256), 0, stream>>>(p1, p2, gamma, beta, scale, shift);
  k_out  <<<dim3((MM*(CC/4) + 255)/256), dim3(256), 0, stream>>>(x, h, scale, shift, out);
}